// Round 13
// baseline (775.781 us; speedup 1.0000x reference)
//
#include <hip/hip_runtime.h>
#include <math.h>

#define NBINS 255
#define BIN_LO_F (-20.0f)
#define BIN_HI_F (20.0f)

typedef __attribute__((ext_vector_type(8))) short short8;
typedef __attribute__((ext_vector_type(16))) float f32x16;

__device__ __forceinline__ unsigned short f2bf(float f) {
    unsigned u = __builtin_bit_cast(unsigned, f);
    unsigned r = u + 0x7fffu + ((u >> 16) & 1u);
    return (unsigned short)(r >> 16);
}

__device__ __forceinline__ unsigned pkbf(float lo, float hi) {
    unsigned d;
    asm("v_cvt_pk_bf16_f32 %0, %1, %2" : "=v"(d) : "v"(lo), "v"(hi));
    return d;
}

__device__ __forceinline__ short8 mk8(unsigned a, unsigned b, unsigned c, unsigned d) {
    union { unsigned u[4]; short8 s; } t;
    t.u[0] = a; t.u[1] = b; t.u[2] = c; t.u[3] = d;
    return t.s;
}

__device__ __forceinline__ void glds16(const void* g, void* l) {
    __builtin_amdgcn_global_load_lds(
        (const __attribute__((address_space(1))) unsigned int*)g,
        (__attribute__((address_space(3))) unsigned int*)l, 16, 0, 0);
}

__device__ __forceinline__ double wave_reduce_sum_d(double v) {
    #pragma unroll
    for (int m = 32; m >= 1; m >>= 1) v += __shfl_xor(v, m, 64);
    return v;
}

// Pack W (D,255) fp32 -> bf16, 8 KB block per K-step of 16:
// 16B unit u: kt=u>>9, v=u&511: lh=v>>8, gcol=(v>>5)&7, c31=v&31.
// elem e: k = kt*16 + lh*8 + e, col = gcol*32 + c31 (col 255 -> 0 pad).
__global__ __launch_bounds__(256) void pack_w5(
    const float* __restrict__ W, char* __restrict__ WpackB)
{
    int u = blockIdx.x * 256 + threadIdx.x;
    int kt = u >> 9;
    int v  = u & 511;
    int lh = v >> 8;
    int gcol = (v >> 5) & 7;
    int c31  = v & 31;
    int col  = gcol * 32 + c31;
    int k0   = kt * 16 + lh * 8;
    short8 s;
    #pragma unroll
    for (int e = 0; e < 8; ++e)
        s[e] = (col < NBINS) ? (short)f2bf(W[(size_t)(k0 + e) * NBINS + col]) : (short)0;
    *(short8*)(WpackB + (size_t)u * 16) = s;
}

// v12 = v11 with the residency cap raised: __launch_bounds__(256, 6) -> 6 blocks/CU
// (144 KB LDS), 24 waves/CU. Single-variable change vs v11 to isolate occupancy.
// BM=64 x BN=256 x K-quarter, grid 272*split, 4 waves (2M x 2N), wave tile 32x128.
// A: full-line glds (16 rows x 64B per instr), source-chunk XOR, read same XOR.
// B: 2 glds/wave/step from packed image. 2 LDS buffers, counted vmcnt(3).
__global__ __launch_bounds__(256, 6) void gemm_mfma_v12(
    const float* __restrict__ latents, const float* __restrict__ boot,
    const char* __restrict__ WpackB, float* __restrict__ P, size_t Pstride,
    int NR, int R, int D, int split, int nMt, int nwg8)
{
    __shared__ __align__(16) char ldsA[2][4096];
    __shared__ __align__(16) char ldsB[2][8192];

    const int tid  = threadIdx.x;
    const int wave = tid >> 6, lane = tid & 63;
    const int l31  = lane & 31, lhi = lane >> 5;
    const int mw   = wave & 1, nw = wave >> 1;
    const int KQ   = D / split;
    const int NT   = KQ >> 4;                // K-steps of 16 (even)

    // XCD swizzle (nwg % 8 == 0 -> bijective); kq-major work order
    int bid  = blockIdx.x;
    int work = (bid & 7) * nwg8 + (bid >> 3);
    const int kq = work / nMt;
    const int mt = work - kq * nMt;
    const int row0 = mt * 64;
    float* __restrict__ Pq = P + (size_t)kq * Pstride;

    // A staging role: rloc = wave*16 + (lane>>2), chunk c = lane&3 (16B units);
    // source chunk = c ^ ((rloc>>1)&3)
    const int rloc = (wave << 4) + (lane >> 2);
    int arow = row0 + rloc; if (arow > R - 1) arow = R - 1;
    const float* arowp = (arow < NR) ? latents + (size_t)arow * D
                                     : boot + (size_t)(arow - NR) * D;
    const float* asrc = arowp + kq * KQ + (((lane & 3) ^ ((rloc >> 1) & 3)) << 2);

    const char* bbase = WpackB + (size_t)kq * ((size_t)NT * 8192)
                               + (wave << 11) + (lane << 4);

    f32x16 acc[4];
    #pragma unroll
    for (int g = 0; g < 4; ++g)
        #pragma unroll
        for (int r = 0; r < 16; ++r) acc[g][r] = 0.f;

    // A read: row r = mw*32+l31, slot s = 2*lhi (+1); phys = s ^ ((r>>1)&3)
    const int ar   = mw * 32 + l31;
    const int aswz = (ar >> 1) & 3;
    const int aoff0 = ar * 64 + (((2 * lhi)       ^ aswz) << 4);
    const int aoff1 = ar * 64 + ((((2 * lhi) | 1) ^ aswz) << 4);

#define STAGE(T, BUF) do {                                                  \
        glds16(asrc + (size_t)(T) * 16, &ldsA[BUF][(wave << 10) + (lane << 4)]); \
        const char* bs_ = bbase + (size_t)(T) * 8192;                       \
        char* bd_ = &ldsB[BUF][(wave << 11) + (lane << 4)];                 \
        glds16(bs_,        bd_);                                            \
        glds16(bs_ + 1024, bd_ + 1024);                                     \
    } while (0)

#define COMPUTE(BUF) do {                                                   \
        const char* ab_ = &ldsA[BUF][0];                                    \
        const char* bb_ = &ldsB[BUF][0] + (lhi << 12) + (nw << 11) + (l31 << 4); \
        float4 f0_ = *(const float4*)(ab_ + aoff0);                         \
        float4 f1_ = *(const float4*)(ab_ + aoff1);                         \
        short8 a_ = mk8(pkbf(f0_.x, f0_.y), pkbf(f0_.z, f0_.w),             \
                        pkbf(f1_.x, f1_.y), pkbf(f1_.z, f1_.w));            \
        _Pragma("unroll")                                                   \
        for (int g = 0; g < 4; ++g) {                                       \
            short8 b_ = *(const short8*)(bb_ + (g << 9));                   \
            acc[g] = __builtin_amdgcn_mfma_f32_32x32x16_bf16(a_, b_, acc[g], 0, 0, 0); \
        }                                                                   \
    } while (0)

#define BAR()   __builtin_amdgcn_s_barrier()
#define SCHED() __builtin_amdgcn_sched_barrier(0)
#define WAITV3() asm volatile("s_waitcnt vmcnt(3)" ::: "memory")
#define WAITV0() asm volatile("s_waitcnt vmcnt(0)" ::: "memory")

    STAGE(0, 0);

    int t = 0;
    for (; t + 3 < NT; t += 2) {
        BAR(); SCHED(); STAGE(t + 1, 1); SCHED(); WAITV3(); BAR(); SCHED(); COMPUTE(0);
        BAR(); SCHED(); STAGE(t + 2, 0); SCHED(); WAITV3(); BAR(); SCHED(); COMPUTE(1);
    }
    BAR(); SCHED(); STAGE(NT - 1, 1); SCHED(); WAITV3(); BAR(); SCHED(); COMPUTE(0);
    BAR(); SCHED(); WAITV0(); BAR(); SCHED(); COMPUTE(1);

#undef STAGE
#undef COMPUTE
#undef BAR
#undef SCHED
#undef WAITV3
#undef WAITV0

    // epilogue: raw partial store. C layout: col=lane&31, row=(r&3)+8*(r>>2)+4*lhi
    #pragma unroll
    for (int g = 0; g < 4; ++g) {
        int col = nw * 128 + g * 32 + l31;
        #pragma unroll
        for (int r = 0; r < 16; ++r) {
            int row = row0 + mw * 32 + (r & 3) + 8 * (r >> 2) + 4 * lhi;
            Pq[(size_t)row * 256 + col] = acc[g][r];
        }
    }
}

// softmax over l = sum_q P_q + bias: value, logZ per row
__global__ __launch_bounds__(256) void softmax_statsN(
    const float* __restrict__ P, size_t Pstride, int split,
    const float* __restrict__ bvec, float* __restrict__ values,
    float* __restrict__ logZ, int R)
{
    int row  = blockIdx.x * 4 + (threadIdx.x >> 6);
    int lane = threadIdx.x & 63;
    if (row >= R) return;
    const float* pr = P + (size_t)row * 256;
    const float step = (float)(40.0 / 254.0);

    float l[4];
    float m = -INFINITY;
    #pragma unroll
    for (int u = 0; u < 4; ++u) {
        int idx = lane + 64 * u;
        if (idx < NBINS) {
            float s = bvec[idx];
            for (int q = 0; q < split; ++q) s += pr[(size_t)q * Pstride + idx];
            l[u] = s;
        } else l[u] = -INFINITY;
        m = fmaxf(m, l[u]);
    }
    #pragma unroll
    for (int sh = 32; sh >= 1; sh >>= 1) m = fmaxf(m, __shfl_xor(m, sh, 64));

    float s = 0.f, sc = 0.f;
    #pragma unroll
    for (int u = 0; u < 4; ++u) {
        int idx = lane + 64 * u;
        if (idx < NBINS) {
            float e = __expf(l[u] - m);
            s  += e;
            sc += e * (BIN_LO_F + step * (float)idx);
        }
    }
    #pragma unroll
    for (int sh = 32; sh >= 1; sh >>= 1) {
        s  += __shfl_xor(s, sh, 64);
        sc += __shfl_xor(sc, sh, 64);
    }
    if (lane == 0) {
        values[row] = sc / s;
        logZ[row]   = m + __logf(s);
    }
}

__global__ void lambda_returns_k(
    const float* __restrict__ rewards, const float* __restrict__ dones,
    const float* __restrict__ values, float* __restrict__ returns,
    int B, int H, int NR)
{
    int b = blockIdx.x * blockDim.x + threadIdx.x;
    if (b >= B) return;
    const float gamma = 0.997f;
    const float lam   = 0.95f;
    const float oml   = (float)(1.0 - 0.95);
    float bootv = values[NR + b];
    float g = bootv;
    for (int h = H - 1; h >= 0; --h) {
        float nv   = (h == H - 1) ? bootv : values[b * H + h + 1];
        float mask = 1.0f - dones[b * H + h];
        g = rewards[b * H + h] + gamma * mask * (oml * nv + lam * g);
        returns[b * H + h] = g;
    }
}

__global__ __launch_bounds__(256) void loss_momentsN(
    const float* __restrict__ P, size_t Pstride, int split,
    const float* __restrict__ bvec, const float* __restrict__ logZ,
    const float* __restrict__ values, const float* __restrict__ returns,
    double* __restrict__ accum, int NR)
{
    int row = blockIdx.x * blockDim.x + threadIdx.x;
    double lsum = 0, vsum = 0, v2 = 0, rsum = 0, r2 = 0;
    if (row < NR) {
        float v   = values[row];
        float ret = returns[row];
        float cl  = fminf(fmaxf(ret, BIN_LO_F), BIN_HI_F);
        const float step = (float)(40.0 / 254.0);
        float pos = (cl - BIN_LO_F) / step;
        int low = (int)floorf(pos);
        low = min(max(low, 0), NBINS - 2);
        float frac = pos - (float)low;
        size_t base = (size_t)row * 256;
        float llo = bvec[low], lhi = bvec[low + 1];
        for (int q = 0; q < split; ++q) {
            llo += P[(size_t)q * Pstride + base + low];
            lhi += P[(size_t)q * Pstride + base + low + 1];
        }
        float loss = logZ[row] - (1.f - frac) * llo - frac * lhi;
        lsum = (double)loss;
        vsum = (double)v;   v2 = (double)v * (double)v;
        rsum = (double)ret; r2 = (double)ret * (double)ret;
    }
    lsum = wave_reduce_sum_d(lsum);
    vsum = wave_reduce_sum_d(vsum);
    v2   = wave_reduce_sum_d(v2);
    rsum = wave_reduce_sum_d(rsum);
    r2   = wave_reduce_sum_d(r2);
    if ((threadIdx.x & 63) == 0) {
        atomicAdd(&accum[0], lsum);
        atomicAdd(&accum[1], vsum);
        atomicAdd(&accum[2], v2);
        atomicAdd(&accum[3], rsum);
        atomicAdd(&accum[4], r2);
    }
}

__global__ void finalize_k(const double* __restrict__ accum,
                           float* __restrict__ out, int NR)
{
    if (threadIdx.x == 0 && blockIdx.x == 0) {
        double n  = (double)NR;
        double vl = accum[0] / n;
        double mv = accum[1] / n;
        double vv = (accum[2] - n * mv * mv) / (n - 1.0);
        double mr = accum[3] / n;
        double vr = (accum[4] - n * mr * mr) / (n - 1.0);
        out[0] = (float)(0.5 * vl);
        out[1] = (float)vl;
        out[2] = (float)mv;
        out[3] = (float)mr;
        out[4] = (float)sqrt(vv > 0.0 ? vv : 0.0);
        out[5] = (float)sqrt(vr > 0.0 ? vr : 0.0);
    }
}

extern "C" void kernel_launch(void* const* d_in, const int* in_sizes, int n_in,
                              void* d_out, int out_size, void* d_ws, size_t ws_size,
                              hipStream_t stream) {
    const float* latents = (const float*)d_in[0];
    const float* rewards = (const float*)d_in[1];
    const float* dones   = (const float*)d_in[2];
    const float* boot    = (const float*)d_in[3];
    const float* W       = (const float*)d_in[4];
    const float* bvec    = (const float*)d_in[5];
    float* out = (float*)d_out;

    const int BH = in_sizes[1];          // B*H = 16384
    const int D  = in_sizes[0] / BH;     // 4096
    const int B  = in_sizes[3] / D;      // 1024
    const int H  = BH / B;               // 16
    const int NR = BH;
    const int R  = NR + B;               // 17408

    const size_t Pstride = (size_t)R * 256;
    const size_t fixed   = (size_t)R * 2 * 4 + (size_t)NR * 4 + 512 +
                           (size_t)(D / 16) * 8192 + 4096;
    int split = (ws_size >= 4 * Pstride * 4 + fixed) ? 4 : 2;

    char* ws = (char*)d_ws;
    size_t off = 0;
    float* P = (float*)(ws + off); off += (size_t)split * Pstride * sizeof(float);
    float* values = (float*)(ws + off); off += (size_t)R * sizeof(float);
    float* logZ   = (float*)(ws + off); off += (size_t)R * sizeof(float);
    float* rets   = (float*)(ws + off); off += (size_t)NR * sizeof(float);
    off = (off + 255) & ~(size_t)255;
    double* accum = (double*)(ws + off); off += 64;
    off = (off + 255) & ~(size_t)255;
    char* WpackB  = ws + off; off += (size_t)(D / 16) * 8192;   // 2 MB

    hipMemsetAsync(accum, 0, 64, stream);

    const int packUnits = (D / 16) * 512;            // 16B units
    pack_w5<<<packUnits / 256, 256, 0, stream>>>(W, WpackB);

    const int nMt = R / 64;                          // 272
    const int nwg = nMt * split;                     // 1088 or 544 (8-divisible)
    gemm_mfma_v12<<<nwg, 256, 0, stream>>>(latents, boot, WpackB, P, Pstride,
                                           NR, R, D, split, nMt, nwg / 8);
    softmax_statsN<<<(R + 3) / 4, 256, 0, stream>>>(P, Pstride, split, bvec,
                                                    values, logZ, R);
    lambda_returns_k<<<(B + 255) / 256, 256, 0, stream>>>(rewards, dones, values, rets, B, H, NR);
    loss_momentsN<<<(NR + 255) / 256, 256, 0, stream>>>(P, Pstride, split, bvec, logZ,
                                                        values, rets, accum, NR);
    finalize_k<<<1, 64, 0, stream>>>(accum, out, NR);
}

// Round 14
// 194.720 us; speedup vs baseline: 3.9841x; 3.9841x over previous
//
#include <hip/hip_runtime.h>
#include <math.h>

#define NBINS 255
#define BIN_LO_F (-20.0f)
#define BIN_HI_F (20.0f)

typedef __attribute__((ext_vector_type(8))) short short8;
typedef __attribute__((ext_vector_type(16))) float f32x16;

__device__ __forceinline__ unsigned short f2bf(float f) {
    unsigned u = __builtin_bit_cast(unsigned, f);
    unsigned r = u + 0x7fffu + ((u >> 16) & 1u);
    return (unsigned short)(r >> 16);
}

__device__ __forceinline__ unsigned pkbf(float lo, float hi) {
    unsigned d;
    asm("v_cvt_pk_bf16_f32 %0, %1, %2" : "=v"(d) : "v"(lo), "v"(hi));
    return d;
}

__device__ __forceinline__ short8 mk8(unsigned a, unsigned b, unsigned c, unsigned d) {
    union { unsigned u[4]; short8 s; } t;
    t.u[0] = a; t.u[1] = b; t.u[2] = c; t.u[3] = d;
    return t.s;
}

__device__ __forceinline__ void glds16(const void* g, void* l) {
    __builtin_amdgcn_global_load_lds(
        (const __attribute__((address_space(1))) unsigned int*)g,
        (__attribute__((address_space(3))) unsigned int*)l, 16, 0, 0);
}

__device__ __forceinline__ double wave_reduce_sum_d(double v) {
    #pragma unroll
    for (int m = 32; m >= 1; m >>= 1) v += __shfl_xor(v, m, 64);
    return v;
}

// Pack W (D,255) fp32 -> bf16, 8 KB block per K-step of 16:
// 16B unit u: kt=u>>9, v=u&511: lh=v>>8, gcol=(v>>5)&7, c31=v&31.
// elem e: k = kt*16 + lh*8 + e, col = gcol*32 + c31 (col 255 -> 0 pad).
__global__ __launch_bounds__(256) void pack_w5(
    const float* __restrict__ W, char* __restrict__ WpackB)
{
    int u = blockIdx.x * 256 + threadIdx.x;
    int kt = u >> 9;
    int v  = u & 511;
    int lh = v >> 8;
    int gcol = (v >> 5) & 7;
    int c31  = v & 31;
    int col  = gcol * 32 + c31;
    int k0   = kt * 16 + lh * 8;
    short8 s;
    #pragma unroll
    for (int e = 0; e < 8; ++e)
        s[e] = (col < NBINS) ? (short)f2bf(W[(size_t)(k0 + e) * NBINS + col]) : (short)0;
    *(short8*)(WpackB + (size_t)u * 16) = s;
}

// v14 = v11 kernel byte-identical (launch_bounds (256,4): VGPR 64, no spill; LDS 24KB
// -> HW residency 6 blocks/CU), driven with split=8 so the grid (2176) keeps all CUs
// at their 6-block capacity: 24 waves/CU vs v11's grid-starved ~13.
// BM=64 x BN=256 x K-eighth, 4 waves (2M x 2N), wave tile 32x128, acc 4 x f32x16.
// A: full-line glds (16 rows x 64B per instr), source-chunk XOR, read same XOR.
// B: 2 glds/wave/step from packed image. 2 LDS buffers, counted vmcnt(3).
__global__ __launch_bounds__(256, 4) void gemm_mfma_v14(
    const float* __restrict__ latents, const float* __restrict__ boot,
    const char* __restrict__ WpackB, float* __restrict__ P, size_t Pstride,
    int NR, int R, int D, int split, int nMt, int nwg8)
{
    __shared__ __align__(16) char ldsA[2][4096];
    __shared__ __align__(16) char ldsB[2][8192];

    const int tid  = threadIdx.x;
    const int wave = tid >> 6, lane = tid & 63;
    const int l31  = lane & 31, lhi = lane >> 5;
    const int mw   = wave & 1, nw = wave >> 1;
    const int KQ   = D / split;
    const int NT   = KQ >> 4;                // K-steps of 16 (even)

    // XCD swizzle (nwg % 8 == 0 -> bijective); kq-major work order
    int bid  = blockIdx.x;
    int work = (bid & 7) * nwg8 + (bid >> 3);
    const int kq = work / nMt;
    const int mt = work - kq * nMt;
    const int row0 = mt * 64;
    float* __restrict__ Pq = P + (size_t)kq * Pstride;

    // A staging role: rloc = wave*16 + (lane>>2), chunk c = lane&3 (16B units);
    // source chunk = c ^ ((rloc>>1)&3)
    const int rloc = (wave << 4) + (lane >> 2);
    int arow = row0 + rloc; if (arow > R - 1) arow = R - 1;
    const float* arowp = (arow < NR) ? latents + (size_t)arow * D
                                     : boot + (size_t)(arow - NR) * D;
    const float* asrc = arowp + kq * KQ + (((lane & 3) ^ ((rloc >> 1) & 3)) << 2);

    const char* bbase = WpackB + (size_t)kq * ((size_t)NT * 8192)
                               + (wave << 11) + (lane << 4);

    f32x16 acc[4];
    #pragma unroll
    for (int g = 0; g < 4; ++g)
        #pragma unroll
        for (int r = 0; r < 16; ++r) acc[g][r] = 0.f;

    // A read: row r = mw*32+l31, slot s = 2*lhi (+1); phys = s ^ ((r>>1)&3)
    const int ar   = mw * 32 + l31;
    const int aswz = (ar >> 1) & 3;
    const int aoff0 = ar * 64 + (((2 * lhi)       ^ aswz) << 4);
    const int aoff1 = ar * 64 + ((((2 * lhi) | 1) ^ aswz) << 4);

#define STAGE(T, BUF) do {                                                  \
        glds16(asrc + (size_t)(T) * 16, &ldsA[BUF][(wave << 10) + (lane << 4)]); \
        const char* bs_ = bbase + (size_t)(T) * 8192;                       \
        char* bd_ = &ldsB[BUF][(wave << 11) + (lane << 4)];                 \
        glds16(bs_,        bd_);                                            \
        glds16(bs_ + 1024, bd_ + 1024);                                     \
    } while (0)

#define COMPUTE(BUF) do {                                                   \
        const char* ab_ = &ldsA[BUF][0];                                    \
        const char* bb_ = &ldsB[BUF][0] + (lhi << 12) + (nw << 11) + (l31 << 4); \
        float4 f0_ = *(const float4*)(ab_ + aoff0);                         \
        float4 f1_ = *(const float4*)(ab_ + aoff1);                         \
        short8 a_ = mk8(pkbf(f0_.x, f0_.y), pkbf(f0_.z, f0_.w),             \
                        pkbf(f1_.x, f1_.y), pkbf(f1_.z, f1_.w));            \
        _Pragma("unroll")                                                   \
        for (int g = 0; g < 4; ++g) {                                       \
            short8 b_ = *(const short8*)(bb_ + (g << 9));                   \
            acc[g] = __builtin_amdgcn_mfma_f32_32x32x16_bf16(a_, b_, acc[g], 0, 0, 0); \
        }                                                                   \
    } while (0)

#define BAR()   __builtin_amdgcn_s_barrier()
#define SCHED() __builtin_amdgcn_sched_barrier(0)
#define WAITV3() asm volatile("s_waitcnt vmcnt(3)" ::: "memory")
#define WAITV0() asm volatile("s_waitcnt vmcnt(0)" ::: "memory")

    STAGE(0, 0);

    int t = 0;
    for (; t + 3 < NT; t += 2) {
        BAR(); SCHED(); STAGE(t + 1, 1); SCHED(); WAITV3(); BAR(); SCHED(); COMPUTE(0);
        BAR(); SCHED(); STAGE(t + 2, 0); SCHED(); WAITV3(); BAR(); SCHED(); COMPUTE(1);
    }
    BAR(); SCHED(); STAGE(NT - 1, 1); SCHED(); WAITV3(); BAR(); SCHED(); COMPUTE(0);
    BAR(); SCHED(); WAITV0(); BAR(); SCHED(); COMPUTE(1);

#undef STAGE
#undef COMPUTE
#undef BAR
#undef SCHED
#undef WAITV3
#undef WAITV0

    // epilogue: raw partial store. C layout: col=lane&31, row=(r&3)+8*(r>>2)+4*lhi
    #pragma unroll
    for (int g = 0; g < 4; ++g) {
        int col = nw * 128 + g * 32 + l31;
        #pragma unroll
        for (int r = 0; r < 16; ++r) {
            int row = row0 + mw * 32 + (r & 3) + 8 * (r >> 2) + 4 * lhi;
            Pq[(size_t)row * 256 + col] = acc[g][r];
        }
    }
}

// softmax over l = sum_q P_q + bias: value, logZ per row
__global__ __launch_bounds__(256) void softmax_statsN(
    const float* __restrict__ P, size_t Pstride, int split,
    const float* __restrict__ bvec, float* __restrict__ values,
    float* __restrict__ logZ, int R)
{
    int row  = blockIdx.x * 4 + (threadIdx.x >> 6);
    int lane = threadIdx.x & 63;
    if (row >= R) return;
    const float* pr = P + (size_t)row * 256;
    const float step = (float)(40.0 / 254.0);

    float l[4];
    float m = -INFINITY;
    #pragma unroll
    for (int u = 0; u < 4; ++u) {
        int idx = lane + 64 * u;
        if (idx < NBINS) {
            float s = bvec[idx];
            for (int q = 0; q < split; ++q) s += pr[(size_t)q * Pstride + idx];
            l[u] = s;
        } else l[u] = -INFINITY;
        m = fmaxf(m, l[u]);
    }
    #pragma unroll
    for (int sh = 32; sh >= 1; sh >>= 1) m = fmaxf(m, __shfl_xor(m, sh, 64));

    float s = 0.f, sc = 0.f;
    #pragma unroll
    for (int u = 0; u < 4; ++u) {
        int idx = lane + 64 * u;
        if (idx < NBINS) {
            float e = __expf(l[u] - m);
            s  += e;
            sc += e * (BIN_LO_F + step * (float)idx);
        }
    }
    #pragma unroll
    for (int sh = 32; sh >= 1; sh >>= 1) {
        s  += __shfl_xor(s, sh, 64);
        sc += __shfl_xor(sc, sh, 64);
    }
    if (lane == 0) {
        values[row] = sc / s;
        logZ[row]   = m + __logf(s);
    }
}

__global__ void lambda_returns_k(
    const float* __restrict__ rewards, const float* __restrict__ dones,
    const float* __restrict__ values, float* __restrict__ returns,
    int B, int H, int NR)
{
    int b = blockIdx.x * blockDim.x + threadIdx.x;
    if (b >= B) return;
    const float gamma = 0.997f;
    const float lam   = 0.95f;
    const float oml   = (float)(1.0 - 0.95);
    float bootv = values[NR + b];
    float g = bootv;
    for (int h = H - 1; h >= 0; --h) {
        float nv   = (h == H - 1) ? bootv : values[b * H + h + 1];
        float mask = 1.0f - dones[b * H + h];
        g = rewards[b * H + h] + gamma * mask * (oml * nv + lam * g);
        returns[b * H + h] = g;
    }
}

__global__ __launch_bounds__(256) void loss_momentsN(
    const float* __restrict__ P, size_t Pstride, int split,
    const float* __restrict__ bvec, const float* __restrict__ logZ,
    const float* __restrict__ values, const float* __restrict__ returns,
    double* __restrict__ accum, int NR)
{
    int row = blockIdx.x * blockDim.x + threadIdx.x;
    double lsum = 0, vsum = 0, v2 = 0, rsum = 0, r2 = 0;
    if (row < NR) {
        float v   = values[row];
        float ret = returns[row];
        float cl  = fminf(fmaxf(ret, BIN_LO_F), BIN_HI_F);
        const float step = (float)(40.0 / 254.0);
        float pos = (cl - BIN_LO_F) / step;
        int low = (int)floorf(pos);
        low = min(max(low, 0), NBINS - 2);
        float frac = pos - (float)low;
        size_t base = (size_t)row * 256;
        float llo = bvec[low], lhi = bvec[low + 1];
        for (int q = 0; q < split; ++q) {
            llo += P[(size_t)q * Pstride + base + low];
            lhi += P[(size_t)q * Pstride + base + low + 1];
        }
        float loss = logZ[row] - (1.f - frac) * llo - frac * lhi;
        lsum = (double)loss;
        vsum = (double)v;   v2 = (double)v * (double)v;
        rsum = (double)ret; r2 = (double)ret * (double)ret;
    }
    lsum = wave_reduce_sum_d(lsum);
    vsum = wave_reduce_sum_d(vsum);
    v2   = wave_reduce_sum_d(v2);
    rsum = wave_reduce_sum_d(rsum);
    r2   = wave_reduce_sum_d(r2);
    if ((threadIdx.x & 63) == 0) {
        atomicAdd(&accum[0], lsum);
        atomicAdd(&accum[1], vsum);
        atomicAdd(&accum[2], v2);
        atomicAdd(&accum[3], rsum);
        atomicAdd(&accum[4], r2);
    }
}

__global__ void finalize_k(const double* __restrict__ accum,
                           float* __restrict__ out, int NR)
{
    if (threadIdx.x == 0 && blockIdx.x == 0) {
        double n  = (double)NR;
        double vl = accum[0] / n;
        double mv = accum[1] / n;
        double vv = (accum[2] - n * mv * mv) / (n - 1.0);
        double mr = accum[3] / n;
        double vr = (accum[4] - n * mr * mr) / (n - 1.0);
        out[0] = (float)(0.5 * vl);
        out[1] = (float)vl;
        out[2] = (float)mv;
        out[3] = (float)mr;
        out[4] = (float)sqrt(vv > 0.0 ? vv : 0.0);
        out[5] = (float)sqrt(vr > 0.0 ? vr : 0.0);
    }
}

extern "C" void kernel_launch(void* const* d_in, const int* in_sizes, int n_in,
                              void* d_out, int out_size, void* d_ws, size_t ws_size,
                              hipStream_t stream) {
    const float* latents = (const float*)d_in[0];
    const float* rewards = (const float*)d_in[1];
    const float* dones   = (const float*)d_in[2];
    const float* boot    = (const float*)d_in[3];
    const float* W       = (const float*)d_in[4];
    const float* bvec    = (const float*)d_in[5];
    float* out = (float*)d_out;

    const int BH = in_sizes[1];          // B*H = 16384
    const int D  = in_sizes[0] / BH;     // 4096
    const int B  = in_sizes[3] / D;      // 1024
    const int H  = BH / B;               // 16
    const int NR = BH;
    const int R  = NR + B;               // 17408

    const size_t Pstride = (size_t)R * 256;
    const size_t fixed   = (size_t)R * 2 * 4 + (size_t)NR * 4 + 512 +
                           (size_t)(D / 16) * 8192 + 4096;
    int split = 2;
    if (ws_size >= 8 * Pstride * 4 + fixed)      split = 8;
    else if (ws_size >= 4 * Pstride * 4 + fixed) split = 4;

    char* ws = (char*)d_ws;
    size_t off = 0;
    float* P = (float*)(ws + off); off += (size_t)split * Pstride * sizeof(float);
    float* values = (float*)(ws + off); off += (size_t)R * sizeof(float);
    float* logZ   = (float*)(ws + off); off += (size_t)R * sizeof(float);
    float* rets   = (float*)(ws + off); off += (size_t)NR * sizeof(float);
    off = (off + 255) & ~(size_t)255;
    double* accum = (double*)(ws + off); off += 64;
    off = (off + 255) & ~(size_t)255;
    char* WpackB  = ws + off; off += (size_t)(D / 16) * 8192;   // 2 MB

    hipMemsetAsync(accum, 0, 64, stream);

    const int packUnits = (D / 16) * 512;            // 16B units
    pack_w5<<<packUnits / 256, 256, 0, stream>>>(W, WpackB);

    const int nMt = R / 64;                          // 272
    const int nwg = nMt * split;                     // 2176 / 1088 / 544 (8-divisible)
    gemm_mfma_v14<<<nwg, 256, 0, stream>>>(latents, boot, WpackB, P, Pstride,
                                           NR, R, D, split, nMt, nwg / 8);
    softmax_statsN<<<(R + 3) / 4, 256, 0, stream>>>(P, Pstride, split, bvec,
                                                    values, logZ, R);
    lambda_returns_k<<<(B + 255) / 256, 256, 0, stream>>>(rewards, dones, values, rets, B, H, NR);
    loss_momentsN<<<(NR + 255) / 256, 256, 0, stream>>>(P, Pstride, split, bvec, logZ,
                                                        values, rets, accum, NR);
    finalize_k<<<1, 64, 0, stream>>>(accum, out, NR);
}

// Round 15
// 174.044 us; speedup vs baseline: 4.4574x; 1.1188x over previous
//
#include <hip/hip_runtime.h>
#include <math.h>

#define NBINS 255
#define BIN_LO_F (-20.0f)
#define BIN_HI_F (20.0f)

typedef __attribute__((ext_vector_type(8))) short short8;
typedef __attribute__((ext_vector_type(16))) float f32x16;

__device__ __forceinline__ unsigned short f2bf(float f) {
    unsigned u = __builtin_bit_cast(unsigned, f);
    unsigned r = u + 0x7fffu + ((u >> 16) & 1u);
    return (unsigned short)(r >> 16);
}

__device__ __forceinline__ unsigned pkbf(float lo, float hi) {
    unsigned d;
    asm("v_cvt_pk_bf16_f32 %0, %1, %2" : "=v"(d) : "v"(lo), "v"(hi));
    return d;
}

__device__ __forceinline__ short8 mk8(unsigned a, unsigned b, unsigned c, unsigned d) {
    union { unsigned u[4]; short8 s; } t;
    t.u[0] = a; t.u[1] = b; t.u[2] = c; t.u[3] = d;
    return t.s;
}

__device__ __forceinline__ void glds16(const void* g, void* l) {
    __builtin_amdgcn_global_load_lds(
        (const __attribute__((address_space(1))) unsigned int*)g,
        (__attribute__((address_space(3))) unsigned int*)l, 16, 0, 0);
}

__device__ __forceinline__ double wave_reduce_sum_d(double v) {
    #pragma unroll
    for (int m = 32; m >= 1; m >>= 1) v += __shfl_xor(v, m, 64);
    return v;
}

// Pack W (D,255) fp32 -> bf16 image, one 32 KB block per K-tile of 64:
// 16B unit u: kt=u>>11, v=u&2047: ks=v>>9, lh=(v>>8)&1, col=v&255.
// elem e: k = kt*64 + ks*16 + lh*8 + e, column col (255 -> zero pad).
// GEMM B-frag read (ks,lhi,colgroup) is linear 16B/lane -> conflict-free.
__global__ __launch_bounds__(256) void pack_w6(
    const float* __restrict__ W, char* __restrict__ Wimg)
{
    int u = blockIdx.x * 256 + threadIdx.x;
    int kt = u >> 11;
    int v  = u & 2047;
    int ks = v >> 9;
    int lh = (v >> 8) & 1;
    int col = v & 255;
    int k0  = kt * 64 + ks * 16 + lh * 8;
    short8 s;
    #pragma unroll
    for (int e = 0; e < 8; ++e)
        s[e] = (col < NBINS) ? (short)f2bf(W[(size_t)(k0 + e) * NBINS + col]) : (short)0;
    *(short8*)(Wimg + (size_t)u * 16) = s;
}

// v15: fat-phase GEMM (m97-shaped). BM=128 x BN=256 x BK=64, split-4 -> grid 544,
// NT=16 -> 34 barrier-phases/CU (8x fewer than v9/v11 at ~1400 cyc/phase invariant).
// 512 thr = 8 waves (2M x 4N), wave tile 64x64, acc 4 x f32x16 (AGPR).
// Single-buffer 64 KB LDS (2 blocks/CU): A fp32 32 KB (full-line glds, 16B-unit XOR
// swizzle u^(row&15), both sides); B bf16 32 KB (contiguous image, linear reads).
// Phase: STAGE(8 glds/wave); vmcnt(0); BAR; COMPUTE(24 ds_read + 16 MFMA/wave); BAR.
__global__ __launch_bounds__(512, 4) void gemm_mfma_v15(
    const float* __restrict__ latents, const float* __restrict__ boot,
    const char* __restrict__ Wimg, float* __restrict__ P, size_t Pstride,
    int NR, int R, int D, int split, int nMt, int nwg8)
{
    __shared__ __align__(16) char ldsA[32768];
    __shared__ __align__(16) char ldsB[32768];

    const int tid  = threadIdx.x;
    const int wave = tid >> 6, lane = tid & 63;
    const int l31  = lane & 31, lhi = lane >> 5;
    const int mw   = wave & 1, nw = wave >> 1;   // M half (64 rows), N quarter (64 cols)
    const int KQ   = D / split;
    const int NT   = KQ >> 6;                    // phases of BK=64

    // XCD swizzle (nwg % 8 == 0 -> bijective); kq-major
    int bid  = blockIdx.x;
    int work = (bid & 7) * nwg8 + (bid >> 3);
    const int kq = work / nMt;
    const int mt = work - kq * nMt;
    const int row0 = mt * 128;
    float* __restrict__ Pq = P + (size_t)kq * Pstride;

    // R = nMt*128 exactly and NR = 128*128: each block is purely latents or boot.
    const float* Abase = (row0 < NR) ? latents + (size_t)row0 * D
                                     : boot + (size_t)(row0 - NR) * D;

    // A staging: instr j (0..3): row_loc = wave*16 + j*4 + (lane>>4), unit u' = lane&15;
    // source unit = u' ^ (row_loc & 15) (both-sides involution).
    const int au  = lane & 15;
    const int rl0 = (wave << 4) + 0  + (lane >> 4);
    const int rl1 = (wave << 4) + 4  + (lane >> 4);
    const int rl2 = (wave << 4) + 8  + (lane >> 4);
    const int rl3 = (wave << 4) + 12 + (lane >> 4);
    const float* asrc0 = Abase + (size_t)rl0 * D + kq * KQ + ((au ^ (rl0 & 15)) << 2);
    const float* asrc1 = Abase + (size_t)rl1 * D + kq * KQ + ((au ^ (rl1 & 15)) << 2);
    const float* asrc2 = Abase + (size_t)rl2 * D + kq * KQ + ((au ^ (rl2 & 15)) << 2);
    const float* asrc3 = Abase + (size_t)rl3 * D + kq * KQ + ((au ^ (rl3 & 15)) << 2);

    const char* bsrc = Wimg + ((size_t)kq * NT) * 32768 + (wave << 12) + (lane << 4);
    const int sdst = (wave << 12) + (lane << 4);     // 4 KB/wave slice (A and B)

    f32x16 acc00, acc01, acc10, acc11;
    #pragma unroll
    for (int r = 0; r < 16; ++r) { acc00[r] = 0.f; acc01[r] = 0.f; acc10[r] = 0.f; acc11[r] = 0.f; }

    // A read: rows ar0 = mw*64 + l31 (rg0), ar1 = ar0 + 32 (rg1); same &15.
    const int ar0 = mw * 64 + l31;
    const int ar1 = ar0 + 32;
    const int ax  = ar0 & 15;                        // == ar1 & 15
    // B read: addr(ks,cg) = (ks*2+lhi)*4096 + (nw*64 + cg*32 + l31)*16
    const int boff = (lhi << 12) + ((nw * 64 + l31) << 4);

    for (int t = 0; t < NT; ++t) {
        // ---- STAGE(t): 8 glds/wave ----
        {
            const size_t ko = (size_t)t * 64;
            glds16(asrc0 + ko, &ldsA[(wave << 12) + 0    + (lane << 4)]);
            glds16(asrc1 + ko, &ldsA[(wave << 12) + 1024 + (lane << 4)]);
            glds16(asrc2 + ko, &ldsA[(wave << 12) + 2048 + (lane << 4)]);
            glds16(asrc3 + ko, &ldsA[(wave << 12) + 3072 + (lane << 4)]);
            const char* bs = bsrc + (size_t)t * 32768;
            glds16(bs,        &ldsB[sdst]);
            glds16(bs + 1024, &ldsB[sdst + 1024]);
            glds16(bs + 2048, &ldsB[sdst + 2048]);
            glds16(bs + 3072, &ldsB[sdst + 3072]);
        }
        asm volatile("s_waitcnt vmcnt(0)" ::: "memory");
        __builtin_amdgcn_s_barrier();
        __builtin_amdgcn_sched_barrier(0);
        // ---- COMPUTE(t): 4 ks x (4 A-reads + 2 B-reads + 4 MFMA) ----
        #pragma unroll
        for (int ks = 0; ks < 4; ++ks) {
            const int u0 = ks * 4 + lhi * 2;
            float4 f0 = *(const float4*)(&ldsA[ar0 * 256 + (((u0)     ^ ax) << 4)]);
            float4 f1 = *(const float4*)(&ldsA[ar0 * 256 + (((u0 + 1) ^ ax) << 4)]);
            float4 g0 = *(const float4*)(&ldsA[ar1 * 256 + (((u0)     ^ ax) << 4)]);
            float4 g1 = *(const float4*)(&ldsA[ar1 * 256 + (((u0 + 1) ^ ax) << 4)]);
            short8 a0 = mk8(pkbf(f0.x, f0.y), pkbf(f0.z, f0.w),
                            pkbf(f1.x, f1.y), pkbf(f1.z, f1.w));
            short8 a1 = mk8(pkbf(g0.x, g0.y), pkbf(g0.z, g0.w),
                            pkbf(g1.x, g1.y), pkbf(g1.z, g1.w));
            short8 b0 = *(const short8*)(&ldsB[(ks << 13) + boff]);
            short8 b1 = *(const short8*)(&ldsB[(ks << 13) + boff + 512]);
            acc00 = __builtin_amdgcn_mfma_f32_32x32x16_bf16(a0, b0, acc00, 0, 0, 0);
            acc01 = __builtin_amdgcn_mfma_f32_32x32x16_bf16(a0, b1, acc01, 0, 0, 0);
            acc10 = __builtin_amdgcn_mfma_f32_32x32x16_bf16(a1, b0, acc10, 0, 0, 0);
            acc11 = __builtin_amdgcn_mfma_f32_32x32x16_bf16(a1, b1, acc11, 0, 0, 0);
        }
        __builtin_amdgcn_s_barrier();    // readers done before next stage overwrites
        __builtin_amdgcn_sched_barrier(0);
    }

    // epilogue: raw partials. C layout: col=lane&31, row=(r&3)+8*(r>>2)+4*lhi
    #pragma unroll
    for (int rg = 0; rg < 2; ++rg) {
        #pragma unroll
        for (int cg = 0; cg < 2; ++cg) {
            const f32x16& a = rg ? (cg ? acc11 : acc10) : (cg ? acc01 : acc00);
            int col = nw * 64 + cg * 32 + l31;
            if (col < NBINS) {
                #pragma unroll
                for (int r = 0; r < 16; ++r) {
                    int row = row0 + mw * 64 + rg * 32 + (r & 3) + 8 * (r >> 2) + 4 * lhi;
                    Pq[(size_t)row * 256 + col] = a[r];
                }
            }
        }
    }
}

// softmax over l = sum_q P_q + bias: value, logZ per row
__global__ __launch_bounds__(256) void softmax_statsN(
    const float* __restrict__ P, size_t Pstride, int split,
    const float* __restrict__ bvec, float* __restrict__ values,
    float* __restrict__ logZ, int R)
{
    int row  = blockIdx.x * 4 + (threadIdx.x >> 6);
    int lane = threadIdx.x & 63;
    if (row >= R) return;
    const float* pr = P + (size_t)row * 256;
    const float step = (float)(40.0 / 254.0);

    float l[4];
    float m = -INFINITY;
    #pragma unroll
    for (int u = 0; u < 4; ++u) {
        int idx = lane + 64 * u;
        if (idx < NBINS) {
            float s = bvec[idx];
            for (int q = 0; q < split; ++q) s += pr[(size_t)q * Pstride + idx];
            l[u] = s;
        } else l[u] = -INFINITY;
        m = fmaxf(m, l[u]);
    }
    #pragma unroll
    for (int sh = 32; sh >= 1; sh >>= 1) m = fmaxf(m, __shfl_xor(m, sh, 64));

    float s = 0.f, sc = 0.f;
    #pragma unroll
    for (int u = 0; u < 4; ++u) {
        int idx = lane + 64 * u;
        if (idx < NBINS) {
            float e = __expf(l[u] - m);
            s  += e;
            sc += e * (BIN_LO_F + step * (float)idx);
        }
    }
    #pragma unroll
    for (int sh = 32; sh >= 1; sh >>= 1) {
        s  += __shfl_xor(s, sh, 64);
        sc += __shfl_xor(sc, sh, 64);
    }
    if (lane == 0) {
        values[row] = sc / s;
        logZ[row]   = m + __logf(s);
    }
}

__global__ void lambda_returns_k(
    const float* __restrict__ rewards, const float* __restrict__ dones,
    const float* __restrict__ values, float* __restrict__ returns,
    int B, int H, int NR)
{
    int b = blockIdx.x * blockDim.x + threadIdx.x;
    if (b >= B) return;
    const float gamma = 0.997f;
    const float lam   = 0.95f;
    const float oml   = (float)(1.0 - 0.95);
    float bootv = values[NR + b];
    float g = bootv;
    for (int h = H - 1; h >= 0; --h) {
        float nv   = (h == H - 1) ? bootv : values[b * H + h + 1];
        float mask = 1.0f - dones[b * H + h];
        g = rewards[b * H + h] + gamma * mask * (oml * nv + lam * g);
        returns[b * H + h] = g;
    }
}

__global__ __launch_bounds__(256) void loss_momentsN(
    const float* __restrict__ P, size_t Pstride, int split,
    const float* __restrict__ bvec, const float* __restrict__ logZ,
    const float* __restrict__ values, const float* __restrict__ returns,
    double* __restrict__ accum, int NR)
{
    int row = blockIdx.x * blockDim.x + threadIdx.x;
    double lsum = 0, vsum = 0, v2 = 0, rsum = 0, r2 = 0;
    if (row < NR) {
        float v   = values[row];
        float ret = returns[row];
        float cl  = fminf(fmaxf(ret, BIN_LO_F), BIN_HI_F);
        const float step = (float)(40.0 / 254.0);
        float pos = (cl - BIN_LO_F) / step;
        int low = (int)floorf(pos);
        low = min(max(low, 0), NBINS - 2);
        float frac = pos - (float)low;
        size_t base = (size_t)row * 256;
        float llo = bvec[low], lhi = bvec[low + 1];
        for (int q = 0; q < split; ++q) {
            llo += P[(size_t)q * Pstride + base + low];
            lhi += P[(size_t)q * Pstride + base + low + 1];
        }
        float loss = logZ[row] - (1.f - frac) * llo - frac * lhi;
        lsum = (double)loss;
        vsum = (double)v;   v2 = (double)v * (double)v;
        rsum = (double)ret; r2 = (double)ret * (double)ret;
    }
    lsum = wave_reduce_sum_d(lsum);
    vsum = wave_reduce_sum_d(vsum);
    v2   = wave_reduce_sum_d(v2);
    rsum = wave_reduce_sum_d(rsum);
    r2   = wave_reduce_sum_d(r2);
    if ((threadIdx.x & 63) == 0) {
        atomicAdd(&accum[0], lsum);
        atomicAdd(&accum[1], vsum);
        atomicAdd(&accum[2], v2);
        atomicAdd(&accum[3], rsum);
        atomicAdd(&accum[4], r2);
    }
}

__global__ void finalize_k(const double* __restrict__ accum,
                           float* __restrict__ out, int NR)
{
    if (threadIdx.x == 0 && blockIdx.x == 0) {
        double n  = (double)NR;
        double vl = accum[0] / n;
        double mv = accum[1] / n;
        double vv = (accum[2] - n * mv * mv) / (n - 1.0);
        double mr = accum[3] / n;
        double vr = (accum[4] - n * mr * mr) / (n - 1.0);
        out[0] = (float)(0.5 * vl);
        out[1] = (float)vl;
        out[2] = (float)mv;
        out[3] = (float)mr;
        out[4] = (float)sqrt(vv > 0.0 ? vv : 0.0);
        out[5] = (float)sqrt(vr > 0.0 ? vr : 0.0);
    }
}

extern "C" void kernel_launch(void* const* d_in, const int* in_sizes, int n_in,
                              void* d_out, int out_size, void* d_ws, size_t ws_size,
                              hipStream_t stream) {
    const float* latents = (const float*)d_in[0];
    const float* rewards = (const float*)d_in[1];
    const float* dones   = (const float*)d_in[2];
    const float* boot    = (const float*)d_in[3];
    const float* W       = (const float*)d_in[4];
    const float* bvec    = (const float*)d_in[5];
    float* out = (float*)d_out;

    const int BH = in_sizes[1];          // B*H = 16384
    const int D  = in_sizes[0] / BH;     // 4096
    const int B  = in_sizes[3] / D;      // 1024
    const int H  = BH / B;               // 16
    const int NR = BH;
    const int R  = NR + B;               // 17408 = 136 * 128

    const size_t Pstride = (size_t)R * 256;
    const size_t fixed   = (size_t)R * 2 * 4 + (size_t)NR * 4 + 512 +
                           (size_t)(D / 64) * 32768 + 4096;
    int split = (ws_size >= 4 * Pstride * 4 + fixed) ? 4 : 2;

    char* ws = (char*)d_ws;
    size_t off = 0;
    float* P = (float*)(ws + off); off += (size_t)split * Pstride * sizeof(float);
    float* values = (float*)(ws + off); off += (size_t)R * sizeof(float);
    float* logZ   = (float*)(ws + off); off += (size_t)R * sizeof(float);
    float* rets   = (float*)(ws + off); off += (size_t)NR * sizeof(float);
    off = (off + 255) & ~(size_t)255;
    double* accum = (double*)(ws + off); off += 64;
    off = (off + 255) & ~(size_t)255;
    char* Wimg    = ws + off; off += (size_t)(D / 64) * 32768;   // 2 MB

    hipMemsetAsync(accum, 0, 64, stream);

    const int packUnits = (D / 64) * 2048;           // 16B units
    pack_w6<<<packUnits / 256, 256, 0, stream>>>(W, Wimg);

    const int nMt = R / 128;                         // 136
    const int nwg = nMt * split;                     // 544 or 272
    gemm_mfma_v15<<<nwg, 512, 0, stream>>>(latents, boot, Wimg, P, Pstride,
                                           NR, R, D, split, nMt, nwg / 8);
    softmax_statsN<<<(R + 3) / 4, 256, 0, stream>>>(P, Pstride, split, bvec,
                                                    values, logZ, R);
    lambda_returns_k<<<(B + 255) / 256, 256, 0, stream>>>(rewards, dones, values, rets, B, H, NR);
    loss_momentsN<<<(NR + 255) / 256, 256, 0, stream>>>(P, Pstride, split, bvec, logZ,
                                                        values, rets, accum, NR);
    finalize_k<<<1, 64, 0, stream>>>(accum, out, NR);
}